// Round 4
// baseline (316.750 us; speedup 1.0000x reference)
//
#include <hip/hip_runtime.h>

#define A_ALLELES 4096
#define CCH 12     // input channels
#define LW 32      // read window length
#define DH 32      // hidden dim
#define RDF (CCH * LW)          // floats per read = 384

typedef __attribute__((ext_vector_type(8)))  short bf16x8;   // 4 VGPRs
typedef __attribute__((ext_vector_type(16))) float f32x16;   // 16 VGPRs

// pack two fp32 -> two bf16 (round-half-up; proven numerics from R0 baseline)
__device__ inline unsigned pk2(float fa, float fb) {
    const unsigned a = __float_as_uint(fa), b = __float_as_uint(fb);
    return ((a + 0x8000u) >> 16) | ((b + 0x8000u) & 0xffff0000u);
}

// ---------------------------------------------------------------------------
// Kernel 1: exclusive prefix-sum of the two per-allele read-count arrays.
// ---------------------------------------------------------------------------
__global__ __launch_bounds__(256) void scan_kernel(
    const int* __restrict__ c0, const int* __restrict__ c1,
    int* __restrict__ o0, int* __restrict__ o1)
{
    const int* c = (blockIdx.x == 0) ? c0 : c1;
    int*       o = (blockIdx.x == 0) ? o0 : o1;

    __shared__ int part[256];
    const int tid  = threadIdx.x;
    const int base = tid * 16;

    int loc[16];
    int s = 0;
#pragma unroll
    for (int i = 0; i < 16; ++i) { loc[i] = c[base + i]; s += loc[i]; }
    part[tid] = s;
    __syncthreads();

    for (int st = 1; st < 256; st <<= 1) {
        int v = (tid >= st) ? part[tid - st] : 0;
        __syncthreads();
        part[tid] += v;
        __syncthreads();
    }

    int excl = (tid == 0) ? 0 : part[tid - 1];
#pragma unroll
    for (int i = 0; i < 16; ++i) { o[base + i] = excl; excl += loc[i]; }
}

// ---------------------------------------------------------------------------
// Kernel 2: one wave per (allele, src). DEPTH-4 rotating register pipeline,
// ENTIRELY compiler-scheduled: no inline asm anywhere (R2/R3's hand-counted
// vmcnt waits NaN'd because the scheduler's instruction order need not match
// the hand count; the backend's own waitcnt insertion is correct against its
// final order, as R0/R1 proved). Prologue issues reads 0..3 (32 dword loads,
// ~8 KB in flight/wave); each loop step consumes one read (pk2 -> one
// 32x32x16 bf16 MFMA -> relu-acc) and prefetches read i+4. Counts are 16/24
// (multiples of 4) -> clean drain; generic depth-1 tail kept for safety.
// A = W (A[m=d=lane&31][k=(lane>>5)*8+j], zeros at k>=12); B per lane
// (h=lane>>5, l=lane&31) = t[c][l] via pLo/pHi (h=1's j>=4 elems dead but
// finite). Bias via C operand. Epilogue: shfl-reduce over l, fold
// 1/(32*depth) + W2 head, 2 atomics/(a,src). LDS = 0.5 KB.
// ---------------------------------------------------------------------------
__global__ __launch_bounds__(256, 4) void main_kernel(
    const float* __restrict__ t0, const float* __restrict__ t1,
    const float* __restrict__ W0, const float* __restrict__ b0,
    const float* __restrict__ W1, const float* __restrict__ b1,
    const float* __restrict__ W2, const float* __restrict__ b2,
    const int*  __restrict__ cnt0, const int* __restrict__ cnt1,
    const float* __restrict__ dm0, const float* __restrict__ dm1,
    const int*  __restrict__ offs0, const int* __restrict__ offs1,
    float* __restrict__ out)
{
    __shared__ float sW2[2 * 2 * DH];    // [NOUT][2D] flat = 128
    __shared__ float sB2[2];

    const int tid = threadIdx.x;
    if (tid < 2 * 2 * DH) sW2[tid] = W2[tid];
    if (tid < 2) sB2[tid] = b2[tid];
    __syncthreads();                     // once; main loop is barrier-free

    const int w    = tid >> 6;
    const int lane = tid & 63;
    const int src  = blockIdx.x >> 10;                  // block-uniform
    const int a    = ((blockIdx.x & 1023) << 2) | w;    // 0..4095

    const float* __restrict__ tens = src ? t1 : t0;
    const int*   __restrict__ cnt  = src ? cnt1 : cnt0;
    const int*   __restrict__ offs = src ? offs1 : offs0;
    const float* __restrict__ dm   = src ? dm1 : dm0;
    const float* __restrict__ gW   = src ? W1 : W0;
    const float* __restrict__ gB   = src ? b1 : b0;

    const int l = lane & 31;             // B column / D column
    const int h = lane >> 5;             // k-half selector

    // ---- hoisted: A fragment from W: A[m=d=l][k=h*8+j], zero k>=12 -------
    union { bf16x8 v; unsigned u[4]; } Af;
#pragma unroll
    for (int p = 0; p < 4; ++p) {
        const int c0 = h * 8 + 2 * p, c1 = c0 + 1;
        const float f0 = (c0 < CCH) ? gW[l * CCH + c0] : 0.f;
        const float f1 = (c1 < CCH) ? gW[l * CCH + c1] : 0.f;
        Af.u[p] = pk2(f0, f1);
    }
    // ---- hoisted: bias via C operand: C[row=d][col] = b[d] ---------------
    f32x16 cb;
#pragma unroll
    for (int reg = 0; reg < 16; ++reg)
        cb[reg] = gB[(reg & 3) + 8 * (reg >> 2) + 4 * h];

    const int n     = cnt[a];
    const int start = offs[a];
    const float* rb  = tens + (size_t)start * RDF;
    const float* pLo = rb + l + h * 256;             // c = h*8 + j,  j=0..3
    const float* pHi = rb + l + (h ? 256 : 128);     // c = 4..7 (h0) / 8..11 (h1)

    float acc[16];
#pragma unroll
    for (int r = 0; r < 16; ++r) acc[r] = 0.f;

#define LOADR(B, i) do {                                              \
        const float* _pL = pLo + (size_t)(i) * RDF;                   \
        const float* _pH = pHi + (size_t)(i) * RDF;                   \
        B[0] = _pL[0];  B[1] = _pL[32]; B[2] = _pL[64]; B[3] = _pL[96]; \
        B[4] = _pH[0];  B[5] = _pH[32]; B[6] = _pH[64]; B[7] = _pH[96]; } while (0)

#define CONSUME(B) do {                                               \
        union { bf16x8 v; unsigned u[4]; } Bf;                        \
        Bf.u[0] = pk2(B[0], B[1]); Bf.u[1] = pk2(B[2], B[3]);         \
        Bf.u[2] = pk2(B[4], B[5]); Bf.u[3] = pk2(B[6], B[7]);         \
        const f32x16 Dv = __builtin_amdgcn_mfma_f32_32x32x16_bf16(    \
            Af.v, Bf.v, cb, 0, 0, 0);                                 \
        _Pragma("unroll")                                             \
        for (int r_ = 0; r_ < 16; ++r_) acc[r_] += fmaxf(Dv[r_], 0.f); } while (0)

    const int nf = n & ~3;               // full 4-read groups (n is 16/24)
    if (nf >= 4) {
        float B0[8], B1[8], B2[8], B3[8];
        LOADR(B0, 0); LOADR(B1, 1); LOADR(B2, 2); LOADR(B3, 3);

        for (int g = 0; g + 8 <= nf; g += 4) {
            CONSUME(B0); LOADR(B0, g + 4);
            CONSUME(B1); LOADR(B1, g + 5);
            CONSUME(B2); LOADR(B2, g + 6);
            CONSUME(B3); LOADR(B3, g + 7);
        }
        // drain: reads nf-4 .. nf-1
        CONSUME(B0); CONSUME(B1); CONSUME(B2); CONSUME(B3);
    }
    for (int i = nf; i < n; ++i) {       // safety tail (counts are 16/24)
        float BT[8];
        LOADR(BT, i);
        CONSUME(BT);
    }
#undef LOADR
#undef CONSUME

    // reduce over l (cols): masks 1..16 stay within each 32-lane half
#pragma unroll
    for (int r = 0; r < 16; ++r) {
#pragma unroll
        for (int mm = 1; mm < 32; mm <<= 1)
            acc[r] += __shfl_xor(acc[r], mm, 64);
    }

    const float scale = 1.f / (32.f * dm[a]);
    float c0s = 0.f, c1s = 0.f;
#pragma unroll
    for (int r = 0; r < 16; ++r) {
        const int d = (r & 3) + 8 * (r >> 2) + 4 * h;
        const float pv = acc[r] * scale;     // pooled[a, src*32 + d]
        c0s = fmaf(pv, sW2[0 * 2 * DH + src * DH + d], c0s);
        c1s = fmaf(pv, sW2[1 * 2 * DH + src * DH + d], c1s);
    }
    // combine the two h-halves (each held 16 of the 32 d's)
    c0s += __shfl_xor(c0s, 32, 64);
    c1s += __shfl_xor(c1s, 32, 64);

    if (lane == 0) {
        if (src == 0) { c0s += sB2[0]; c1s += sB2[1]; }
        atomicAdd(&out[a * 2 + 0], c0s);
        atomicAdd(&out[a * 2 + 1], c1s);
    }
}

extern "C" void kernel_launch(void* const* d_in, const int* in_sizes, int n_in,
                              void* d_out, int out_size, void* d_ws, size_t ws_size,
                              hipStream_t stream) {
    const float* t0  = (const float*)d_in[0];
    const float* t1  = (const float*)d_in[1];
    const float* W0  = (const float*)d_in[2];
    const float* b0  = (const float*)d_in[3];
    const float* W1  = (const float*)d_in[4];
    const float* b1  = (const float*)d_in[5];
    const float* W2  = (const float*)d_in[6];
    const float* b2  = (const float*)d_in[7];
    const int*  cnt0 = (const int*)d_in[8];
    const int*  cnt1 = (const int*)d_in[9];
    // d_in[10] = numAllelesPerSite (unused by the reference math)
    const float* dm0 = (const float*)d_in[11];
    const float* dm1 = (const float*)d_in[12];

    int* offs0 = (int*)d_ws;
    int* offs1 = offs0 + A_ALLELES;

    hipMemsetAsync(d_out, 0, (size_t)out_size * sizeof(float), stream);
    scan_kernel<<<2, 256, 0, stream>>>(cnt0, cnt1, offs0, offs1);

    main_kernel<<<2048, 256, 0, stream>>>(
        t0, t1, W0, b0, W1, b1, W2, b2,
        cnt0, cnt1, dm0, dm1, offs0, offs1, (float*)d_out);
}

// Round 5
// 298.222 us; speedup vs baseline: 1.0621x; 1.0621x over previous
//
#include <hip/hip_runtime.h>

#define A_ALLELES 4096
#define CCH 12     // input channels
#define LW 32      // read window length
#define DH 32      // hidden dim
#define RDF (CCH * LW)          // floats per read = 384

typedef __attribute__((ext_vector_type(8)))  short bf16x8;   // 4 VGPRs
typedef __attribute__((ext_vector_type(16))) float f32x16;   // 16 VGPRs

// pack two fp32 -> two bf16 (round-half-up; proven numerics from R0 baseline)
__device__ inline unsigned pk2(float fa, float fb) {
    const unsigned a = __float_as_uint(fa), b = __float_as_uint(fb);
    return ((a + 0x8000u) >> 16) | ((b + 0x8000u) & 0xffff0000u);
}

// ---------------------------------------------------------------------------
// Kernel 1: exclusive prefix-sum of the two per-allele read-count arrays.
// ---------------------------------------------------------------------------
__global__ __launch_bounds__(256) void scan_kernel(
    const int* __restrict__ c0, const int* __restrict__ c1,
    int* __restrict__ o0, int* __restrict__ o1)
{
    const int* c = (blockIdx.x == 0) ? c0 : c1;
    int*       o = (blockIdx.x == 0) ? o0 : o1;

    __shared__ int part[256];
    const int tid  = threadIdx.x;
    const int base = tid * 16;

    int loc[16];
    int s = 0;
#pragma unroll
    for (int i = 0; i < 16; ++i) { loc[i] = c[base + i]; s += loc[i]; }
    part[tid] = s;
    __syncthreads();

    for (int st = 1; st < 256; st <<= 1) {
        int v = (tid >= st) ? part[tid - st] : 0;
        __syncthreads();
        part[tid] += v;
        __syncthreads();
    }

    int excl = (tid == 0) ? 0 : part[tid - 1];
#pragma unroll
    for (int i = 0; i < 16; ++i) { o[base + i] = excl; excl += loc[i]; }
}

// ---------------------------------------------------------------------------
// Kernel 2: one wave per (allele, src). WIDE-LOAD depth-2 register pipeline:
// each read fetched by 3 x global_load_dwordx2 (8 B/lane, 192 requests/read
// vs R0's 512 x 4B; zero dead bytes - exactly the read's 24 cache lines).
// Lane decomposition: e=lane&1, j=(lane>>1)&15, half=lane>>5. Instr q0 loads
// channel c=(half*8+e) cols 2j..2j+1; q1: c=half*8+2+e; q2: c=4+2*half+e.
// Redistribution: shfl_xor(1) + select-by-e gives each lane t[c][l] for the
// channel pair; q2's (c6,c7) [computed in lanes 32..63] crosses to lanes
// 0..31 via shfl_xor(32). h=1 lanes' k=12..15 B-slots receive finite junk,
// multiplied by the zero A-fragment rows (k>=12) -> no effect.
// MFMA/bias/relu/acc/epilogue identical to the R0-verified kernel.
// Depth-2, fully compiler-scheduled (no inline asm; R2/R3's hand-counted
// vmcnt NaN'd, R4's depth-4 spilled).
// ---------------------------------------------------------------------------
__global__ __launch_bounds__(256, 4) void main_kernel(
    const float* __restrict__ t0, const float* __restrict__ t1,
    const float* __restrict__ W0, const float* __restrict__ b0,
    const float* __restrict__ W1, const float* __restrict__ b1,
    const float* __restrict__ W2, const float* __restrict__ b2,
    const int*  __restrict__ cnt0, const int* __restrict__ cnt1,
    const float* __restrict__ dm0, const float* __restrict__ dm1,
    const int*  __restrict__ offs0, const int* __restrict__ offs1,
    float* __restrict__ out)
{
    __shared__ float sW2[2 * 2 * DH];    // [NOUT][2D] flat = 128
    __shared__ float sB2[2];

    const int tid = threadIdx.x;
    if (tid < 2 * 2 * DH) sW2[tid] = W2[tid];
    if (tid < 2) sB2[tid] = b2[tid];
    __syncthreads();                     // once; main loop is barrier-free

    const int w    = tid >> 6;
    const int lane = tid & 63;
    const int src  = blockIdx.x >> 10;                  // block-uniform
    const int a    = ((blockIdx.x & 1023) << 2) | w;    // 0..4095

    const float* __restrict__ tens = src ? t1 : t0;
    const int*   __restrict__ cnt  = src ? cnt1 : cnt0;
    const int*   __restrict__ offs = src ? offs1 : offs0;
    const float* __restrict__ dm   = src ? dm1 : dm0;
    const float* __restrict__ gW   = src ? W1 : W0;
    const float* __restrict__ gB   = src ? b1 : b0;

    const int l = lane & 31;             // B column / D column
    const int h = lane >> 5;             // k-half selector

    // ---- hoisted: A fragment from W: A[m=d=l][k=h*8+j], zero k>=12 -------
    union { bf16x8 v; unsigned u[4]; } Af;
#pragma unroll
    for (int p = 0; p < 4; ++p) {
        const int c0 = h * 8 + 2 * p, c1 = c0 + 1;
        const float f0 = (c0 < CCH) ? gW[l * CCH + c0] : 0.f;
        const float f1 = (c1 < CCH) ? gW[l * CCH + c1] : 0.f;
        Af.u[p] = pk2(f0, f1);
    }
    // ---- hoisted: bias via C operand: C[row=d][col] = b[d] ---------------
    f32x16 cb;
#pragma unroll
    for (int reg = 0; reg < 16; ++reg)
        cb[reg] = gB[(reg & 3) + 8 * (reg >> 2) + 4 * h];

    const int n     = cnt[a];
    const int start = offs[a];
    const float* rb = tens + (size_t)start * RDF;

    // ---- wide-load lane mapping ------------------------------------------
    const int e    = lane & 1;           // element / channel-parity selector
    const int jj   = (lane >> 1) & 15;   // column pair index (l = 2*jj + e)
    const int half = lane >> 5;          // 0: loads c0..5-group, 1: c6..11
    // float offsets of the three float2 loads within a read
    const int q0 = 2 * ((half * 8 + e)     * 16 + jj);  // c = 0/1  | 8/9
    const int q1 = 2 * ((half * 8 + 2 + e) * 16 + jj);  // c = 2/3  | 10/11
    const int q2 = 2 * ((4 + half * 2 + e) * 16 + jj);  // c = 4/5  | 6/7

    float acc[16];
#pragma unroll
    for (int r = 0; r < 16; ++r) acc[r] = 0.f;

#define LOADF2(A0, A1, A2, i) do {                                    \
        const float* _p = rb + (size_t)(i) * RDF;                     \
        A0 = *reinterpret_cast<const float2*>(_p + q0);               \
        A1 = *reinterpret_cast<const float2*>(_p + q1);               \
        A2 = *reinterpret_cast<const float2*>(_p + q2); } while (0)

#define CONSUMEF2(A0, A1, A2) do {                                    \
        const float p0x = __shfl_xor(A0.x, 1, 64);                    \
        const float p0y = __shfl_xor(A0.y, 1, 64);                    \
        const float p1x = __shfl_xor(A1.x, 1, 64);                    \
        const float p1y = __shfl_xor(A1.y, 1, 64);                    \
        const float p2x = __shfl_xor(A2.x, 1, 64);                    \
        const float p2y = __shfl_xor(A2.y, 1, 64);                    \
        const float c0v = e ? p0y : A0.x;   /* c0  | c8  at col l */  \
        const float c1v = e ? A0.y : p0x;   /* c1  | c9            */ \
        const float c2v = e ? p1y : A1.x;   /* c2  | c10           */ \
        const float c3v = e ? A1.y : p1x;   /* c3  | c11           */ \
        const float vA  = e ? p2y : A2.x;   /* c4  | c6            */ \
        const float vB  = e ? A2.y : p2x;   /* c5  | c7            */ \
        const float vC  = __shfl_xor(vA, 32, 64);  /* c6 to h=0 */    \
        const float vD  = __shfl_xor(vB, 32, 64);  /* c7 to h=0 */    \
        union { bf16x8 v; unsigned u[4]; } Bf;                        \
        Bf.u[0] = pk2(c0v, c1v); Bf.u[1] = pk2(c2v, c3v);             \
        Bf.u[2] = pk2(vA, vB);   Bf.u[3] = pk2(vC, vD);               \
        const f32x16 Dv = __builtin_amdgcn_mfma_f32_32x32x16_bf16(    \
            Af.v, Bf.v, cb, 0, 0, 0);                                 \
        _Pragma("unroll")                                             \
        for (int r_ = 0; r_ < 16; ++r_) acc[r_] += fmaxf(Dv[r_], 0.f); } while (0)

    const int n2 = n & ~1;               // n is 16/24
    if (n2 >= 2) {
        float2 Ra0, Ra1, Ra2, Rb0, Rb1, Rb2;
        LOADF2(Ra0, Ra1, Ra2, 0);
        LOADF2(Rb0, Rb1, Rb2, 1);
        for (int i = 0; i + 4 <= n2; i += 2) {
            CONSUMEF2(Ra0, Ra1, Ra2); LOADF2(Ra0, Ra1, Ra2, i + 2);
            CONSUMEF2(Rb0, Rb1, Rb2); LOADF2(Rb0, Rb1, Rb2, i + 3);
        }
        CONSUMEF2(Ra0, Ra1, Ra2);
        CONSUMEF2(Rb0, Rb1, Rb2);
    }
    for (int i = n2; i < n; ++i) {       // safety tail (counts are 16/24)
        float2 T0, T1, T2;
        LOADF2(T0, T1, T2, i);
        CONSUMEF2(T0, T1, T2);
    }
#undef LOADF2
#undef CONSUMEF2

    // reduce over l (cols): masks 1..16 stay within each 32-lane half
#pragma unroll
    for (int r = 0; r < 16; ++r) {
#pragma unroll
        for (int mm = 1; mm < 32; mm <<= 1)
            acc[r] += __shfl_xor(acc[r], mm, 64);
    }

    const float scale = 1.f / (32.f * dm[a]);
    float c0s = 0.f, c1s = 0.f;
#pragma unroll
    for (int r = 0; r < 16; ++r) {
        const int d = (r & 3) + 8 * (r >> 2) + 4 * h;
        const float pv = acc[r] * scale;     // pooled[a, src*32 + d]
        c0s = fmaf(pv, sW2[0 * 2 * DH + src * DH + d], c0s);
        c1s = fmaf(pv, sW2[1 * 2 * DH + src * DH + d], c1s);
    }
    // combine the two h-halves (each held 16 of the 32 d's)
    c0s += __shfl_xor(c0s, 32, 64);
    c1s += __shfl_xor(c1s, 32, 64);

    if (lane == 0) {
        if (src == 0) { c0s += sB2[0]; c1s += sB2[1]; }
        atomicAdd(&out[a * 2 + 0], c0s);
        atomicAdd(&out[a * 2 + 1], c1s);
    }
}

extern "C" void kernel_launch(void* const* d_in, const int* in_sizes, int n_in,
                              void* d_out, int out_size, void* d_ws, size_t ws_size,
                              hipStream_t stream) {
    const float* t0  = (const float*)d_in[0];
    const float* t1  = (const float*)d_in[1];
    const float* W0  = (const float*)d_in[2];
    const float* b0  = (const float*)d_in[3];
    const float* W1  = (const float*)d_in[4];
    const float* b1  = (const float*)d_in[5];
    const float* W2  = (const float*)d_in[6];
    const float* b2  = (const float*)d_in[7];
    const int*  cnt0 = (const int*)d_in[8];
    const int*  cnt1 = (const int*)d_in[9];
    // d_in[10] = numAllelesPerSite (unused by the reference math)
    const float* dm0 = (const float*)d_in[11];
    const float* dm1 = (const float*)d_in[12];

    int* offs0 = (int*)d_ws;
    int* offs1 = offs0 + A_ALLELES;

    hipMemsetAsync(d_out, 0, (size_t)out_size * sizeof(float), stream);
    scan_kernel<<<2, 256, 0, stream>>>(cnt0, cnt1, offs0, offs1);

    main_kernel<<<2048, 256, 0, stream>>>(
        t0, t1, W0, b0, W1, b1, W2, b2,
        cnt0, cnt1, dm0, dm1, offs0, offs1, (float*)d_out);
}

// Round 6
// 293.114 us; speedup vs baseline: 1.0806x; 1.0174x over previous
//
#include <hip/hip_runtime.h>

#define A_ALLELES 4096
#define CCH 12     // input channels
#define LW 32      // read window length
#define DH 32      // hidden dim
#define RDF (CCH * LW)          // floats per read = 384

typedef __attribute__((ext_vector_type(8)))  short bf16x8;   // 4 VGPRs
typedef __attribute__((ext_vector_type(16))) float f32x16;   // 16 VGPRs

// pack two fp32 -> two bf16 (round-half-up; proven numerics from R0 baseline)
__device__ inline unsigned pk2(float fa, float fb) {
    const unsigned a = __float_as_uint(fa), b = __float_as_uint(fb);
    return ((a + 0x8000u) >> 16) | ((b + 0x8000u) & 0xffff0000u);
}

// ---------------------------------------------------------------------------
// Kernel 1: exclusive prefix-sum of the two per-allele read-count arrays.
// ---------------------------------------------------------------------------
__global__ __launch_bounds__(256) void scan_kernel(
    const int* __restrict__ c0, const int* __restrict__ c1,
    int* __restrict__ o0, int* __restrict__ o1)
{
    const int* c = (blockIdx.x == 0) ? c0 : c1;
    int*       o = (blockIdx.x == 0) ? o0 : o1;

    __shared__ int part[256];
    const int tid  = threadIdx.x;
    const int base = tid * 16;

    int loc[16];
    int s = 0;
#pragma unroll
    for (int i = 0; i < 16; ++i) { loc[i] = c[base + i]; s += loc[i]; }
    part[tid] = s;
    __syncthreads();

    for (int st = 1; st < 256; st <<= 1) {
        int v = (tid >= st) ? part[tid - st] : 0;
        __syncthreads();
        part[tid] += v;
        __syncthreads();
    }

    int excl = (tid == 0) ? 0 : part[tid - 1];
#pragma unroll
    for (int i = 0; i < 16; ++i) { o[base + i] = excl; excl += loc[i]; }
}

// ---------------------------------------------------------------------------
// Kernel 2: STREAM-GEOMETRY PROBE. 512 blocks x 4 waves = 2048 waves; wave
// g = blockIdx*4+w serially walks 4 units: {src0,a=g}, {src0,a=g+2048},
// {src1,a=g}, {src1,a=g+2048} -> 4x fewer / 4x longer memory streams than
// the 8192-wave layout (the one untested dimension; width/path/depth/
// dead-bytes all measured null at ~103 us = 2.44 TB/s effective).
// Per unit: R5's wide-load encoding (3 x global_load_dwordx2 per read, zero
// dead bytes, shfl redistribution) at DEPTH-4 (lean: 6 VGPR/read buffer),
// fully compiler-scheduled (no inline asm). __launch_bounds__(256,2) lifts
// the VGPR cap to 256 so depth-4 cannot spill (R4's failure); occupancy is
// grid-limited at 2 blocks/CU regardless.
// Math per unit identical to the R0/R5-verified kernel: A = W fragment
// (A[m=d=lane&31][k=(lane>>5)*8+j], zeros k>=12), bias via C operand,
// relu+acc in 16 regs, shfl-reduce over l, fold 1/(32*depth) + W2 head,
// 2 atomics per (a,src).
// ---------------------------------------------------------------------------
__global__ __launch_bounds__(256, 2) void main_kernel(
    const float* __restrict__ t0, const float* __restrict__ t1,
    const float* __restrict__ W0, const float* __restrict__ b0,
    const float* __restrict__ W1, const float* __restrict__ b1,
    const float* __restrict__ W2, const float* __restrict__ b2,
    const int*  __restrict__ cnt0, const int* __restrict__ cnt1,
    const float* __restrict__ dm0, const float* __restrict__ dm1,
    const int*  __restrict__ offs0, const int* __restrict__ offs1,
    float* __restrict__ out)
{
    __shared__ float sW2[2 * 2 * DH];    // [NOUT][2D] flat = 128
    __shared__ float sB2[2];

    const int tid = threadIdx.x;
    if (tid < 2 * 2 * DH) sW2[tid] = W2[tid];
    if (tid < 2) sB2[tid] = b2[tid];
    __syncthreads();                     // once; main loop is barrier-free

    const int w    = tid >> 6;
    const int lane = tid & 63;
    const int g    = (blockIdx.x << 2) | w;             // 0..2047

    const int l = lane & 31;             // B column / D column
    const int h = lane >> 5;             // k-half selector

    // ---- wide-load lane mapping (unit-independent) -----------------------
    const int e    = lane & 1;           // element / channel-parity selector
    const int jj   = (lane >> 1) & 15;   // column pair index (l = 2*jj + e)
    const int half = lane >> 5;          // 0: loads c0..5-group, 1: c6..11
    const int q0 = 2 * ((half * 8 + e)     * 16 + jj);  // c = 0/1  | 8/9
    const int q1 = 2 * ((half * 8 + 2 + e) * 16 + jj);  // c = 2/3  | 10/11
    const int q2 = 2 * ((4 + half * 2 + e) * 16 + jj);  // c = 4/5  | 6/7

#pragma unroll 1
    for (int k = 0; k < 4; ++k) {
        const int src = k >> 1;                          // 0,0,1,1
        const int a   = g + ((k & 1) << 11);             // g, g+2048

        const float* __restrict__ tens = src ? t1 : t0;
        const int*   __restrict__ cnt  = src ? cnt1 : cnt0;
        const int*   __restrict__ offs = src ? offs1 : offs0;
        const float* __restrict__ dm   = src ? dm1 : dm0;
        const float* __restrict__ gW   = src ? W1 : W0;
        const float* __restrict__ gB   = src ? b1 : b0;

        // ---- A fragment from W: A[m=d=l][k=h*8+j], zero k>=12 ------------
        union { bf16x8 v; unsigned u[4]; } Af;
#pragma unroll
        for (int p = 0; p < 4; ++p) {
            const int c0 = h * 8 + 2 * p, c1 = c0 + 1;
            const float f0 = (c0 < CCH) ? gW[l * CCH + c0] : 0.f;
            const float f1 = (c1 < CCH) ? gW[l * CCH + c1] : 0.f;
            Af.u[p] = pk2(f0, f1);
        }
        // ---- bias via C operand: C[row=d][col] = b[d] --------------------
        f32x16 cb;
#pragma unroll
        for (int reg = 0; reg < 16; ++reg)
            cb[reg] = gB[(reg & 3) + 8 * (reg >> 2) + 4 * h];

        const int n     = cnt[a];
        const int start = offs[a];
        const float* rb = tens + (size_t)start * RDF;

        float acc[16];
#pragma unroll
        for (int r = 0; r < 16; ++r) acc[r] = 0.f;

#define LOADF2(A0, A1, A2, i) do {                                    \
        const float* _p = rb + (size_t)(i) * RDF;                     \
        A0 = *reinterpret_cast<const float2*>(_p + q0);               \
        A1 = *reinterpret_cast<const float2*>(_p + q1);               \
        A2 = *reinterpret_cast<const float2*>(_p + q2); } while (0)

#define CONSUMEF2(A0, A1, A2) do {                                    \
        const float p0x = __shfl_xor(A0.x, 1, 64);                    \
        const float p0y = __shfl_xor(A0.y, 1, 64);                    \
        const float p1x = __shfl_xor(A1.x, 1, 64);                    \
        const float p1y = __shfl_xor(A1.y, 1, 64);                    \
        const float p2x = __shfl_xor(A2.x, 1, 64);                    \
        const float p2y = __shfl_xor(A2.y, 1, 64);                    \
        const float c0v = e ? p0y : A0.x;   /* c0  | c8  at col l */  \
        const float c1v = e ? A0.y : p0x;   /* c1  | c9            */ \
        const float c2v = e ? p1y : A1.x;   /* c2  | c10           */ \
        const float c3v = e ? A1.y : p1x;   /* c3  | c11           */ \
        const float vA  = e ? p2y : A2.x;   /* c4  | c6            */ \
        const float vB  = e ? A2.y : p2x;   /* c5  | c7            */ \
        const float vC  = __shfl_xor(vA, 32, 64);  /* c6 to h=0 */    \
        const float vD  = __shfl_xor(vB, 32, 64);  /* c7 to h=0 */    \
        union { bf16x8 v; unsigned u[4]; } Bf;                        \
        Bf.u[0] = pk2(c0v, c1v); Bf.u[1] = pk2(c2v, c3v);             \
        Bf.u[2] = pk2(vA, vB);   Bf.u[3] = pk2(vC, vD);               \
        const f32x16 Dv = __builtin_amdgcn_mfma_f32_32x32x16_bf16(    \
            Af.v, Bf.v, cb, 0, 0, 0);                                 \
        _Pragma("unroll")                                             \
        for (int r_ = 0; r_ < 16; ++r_) acc[r_] += fmaxf(Dv[r_], 0.f); } while (0)

        const int nf = n & ~3;           // n is 16/24 -> nf == n
        if (nf >= 4) {
            float2 A0, A1, A2, B0, B1, B2, C0, C1, C2, D0, D1, D2;
            LOADF2(A0, A1, A2, 0);
            LOADF2(B0, B1, B2, 1);
            LOADF2(C0, C1, C2, 2);
            LOADF2(D0, D1, D2, 3);
            for (int i = 0; i + 8 <= nf; i += 4) {
                CONSUMEF2(A0, A1, A2); LOADF2(A0, A1, A2, i + 4);
                CONSUMEF2(B0, B1, B2); LOADF2(B0, B1, B2, i + 5);
                CONSUMEF2(C0, C1, C2); LOADF2(C0, C1, C2, i + 6);
                CONSUMEF2(D0, D1, D2); LOADF2(D0, D1, D2, i + 7);
            }
            CONSUMEF2(A0, A1, A2);
            CONSUMEF2(B0, B1, B2);
            CONSUMEF2(C0, C1, C2);
            CONSUMEF2(D0, D1, D2);
        }
        for (int i = nf; i < n; ++i) {   // safety tail (counts are 16/24)
            float2 T0, T1, T2;
            LOADF2(T0, T1, T2, i);
            CONSUMEF2(T0, T1, T2);
        }
#undef LOADF2
#undef CONSUMEF2

        // reduce over l (cols): masks 1..16 stay within each 32-lane half
#pragma unroll
        for (int r = 0; r < 16; ++r) {
#pragma unroll
            for (int mm = 1; mm < 32; mm <<= 1)
                acc[r] += __shfl_xor(acc[r], mm, 64);
        }

        const float scale = 1.f / (32.f * dm[a]);
        float c0s = 0.f, c1s = 0.f;
#pragma unroll
        for (int r = 0; r < 16; ++r) {
            const int d = (r & 3) + 8 * (r >> 2) + 4 * h;
            const float pv = acc[r] * scale;     // pooled[a, src*32 + d]
            c0s = fmaf(pv, sW2[0 * 2 * DH + src * DH + d], c0s);
            c1s = fmaf(pv, sW2[1 * 2 * DH + src * DH + d], c1s);
        }
        // combine the two h-halves (each held 16 of the 32 d's)
        c0s += __shfl_xor(c0s, 32, 64);
        c1s += __shfl_xor(c1s, 32, 64);

        if (lane == 0) {
            if (src == 0) { c0s += sB2[0]; c1s += sB2[1]; }
            atomicAdd(&out[a * 2 + 0], c0s);
            atomicAdd(&out[a * 2 + 1], c1s);
        }
    }
}

extern "C" void kernel_launch(void* const* d_in, const int* in_sizes, int n_in,
                              void* d_out, int out_size, void* d_ws, size_t ws_size,
                              hipStream_t stream) {
    const float* t0  = (const float*)d_in[0];
    const float* t1  = (const float*)d_in[1];
    const float* W0  = (const float*)d_in[2];
    const float* b0  = (const float*)d_in[3];
    const float* W1  = (const float*)d_in[4];
    const float* b1  = (const float*)d_in[5];
    const float* W2  = (const float*)d_in[6];
    const float* b2  = (const float*)d_in[7];
    const int*  cnt0 = (const int*)d_in[8];
    const int*  cnt1 = (const int*)d_in[9];
    // d_in[10] = numAllelesPerSite (unused by the reference math)
    const float* dm0 = (const float*)d_in[11];
    const float* dm1 = (const float*)d_in[12];

    int* offs0 = (int*)d_ws;
    int* offs1 = offs0 + A_ALLELES;

    hipMemsetAsync(d_out, 0, (size_t)out_size * sizeof(float), stream);
    scan_kernel<<<2, 256, 0, stream>>>(cnt0, cnt1, offs0, offs1);

    main_kernel<<<512, 256, 0, stream>>>(
        t0, t1, W0, b0, W1, b1, W2, b2,
        cnt0, cnt1, dm0, dm1, offs0, offs1, (float*)d_out);
}